// Round 11
// baseline (337.924 us; speedup 1.0000x reference)
//
#include <hip/hip_runtime.h>
#include <hip/hip_bf16.h>
#include <stdint.h>

#define DM 1024
#define SEQL 2048
#define NBATCH 4
#define NHEAD 16
#define HDIM 64
#define MTOT (NBATCH * SEQL)  // 8192

using f32x4 = __attribute__((ext_vector_type(4))) float;
using f32x16 = __attribute__((ext_vector_type(16))) float;
using bf16x8 = __attribute__((ext_vector_type(8))) short;

static __device__ __forceinline__ unsigned short f2bf(float f) {
  union { float f; uint32_t u; } v; v.f = f;
  uint32_t u = v.u;
  return (unsigned short)((u + 0x7FFFu + ((u >> 16) & 1u)) >> 16);
}

static __device__ __forceinline__ float exp2_fast(float x) {
#if __has_builtin(__builtin_amdgcn_exp2f)
  return __builtin_amdgcn_exp2f(x);
#else
  float r;
  asm("v_exp_f32 %0, %1" : "=v"(r) : "v"(x));
  return r;
#endif
}

static __device__ __forceinline__ uint32_t pkbf(float lo, float hi) {
  float2 f; f.x = lo; f.y = hi;
  __hip_bfloat162 h = __float22bfloat162_rn(f);
  union { __hip_bfloat162 h; uint32_t u; } cv; cv.h = h;
  return cv.u;
}

static __device__ __forceinline__ f32x16 zero16() {
  f32x16 z;
#pragma unroll
  for (int i = 0; i < 16; ++i) z[i] = 0.f;
  return z;
}

static __device__ __forceinline__ void gload16(const void* g, void* l) {
  __builtin_amdgcn_global_load_lds(
      (const __attribute__((address_space(1))) unsigned int*)g,
      (__attribute__((address_space(3))) unsigned int*)l,
      16, 0, 0);
}

// ---------------- 4x weight transpose + f32->bf16 convert ----------------
__global__ __launch_bounds__(256) void transpose_convert4(
    const float* __restrict__ W0, const float* __restrict__ W1,
    const float* __restrict__ W2, const float* __restrict__ W3,
    unsigned short* __restrict__ T0, unsigned short* __restrict__ T1,
    unsigned short* __restrict__ T2, unsigned short* __restrict__ T3) {
  __shared__ float tile[64][65];
  const int z = blockIdx.z;
  const float* W = z == 0 ? W0 : z == 1 ? W1 : z == 2 ? W2 : W3;
  unsigned short* WT = z == 0 ? T0 : z == 1 ? T1 : z == 2 ? T2 : T3;
  const int bx = blockIdx.x;
  const int by = blockIdx.y;
  const int t = threadIdx.x;
  const int r = t >> 4;
  const int c4 = (t & 15) * 4;
#pragma unroll
  for (int i = 0; i < 4; ++i) {
    const float4 v = *reinterpret_cast<const float4*>(
        &W[(size_t)(by * 64 + r + i * 16) * DM + bx * 64 + c4]);
    tile[r + i * 16][c4 + 0] = v.x;
    tile[r + i * 16][c4 + 1] = v.y;
    tile[r + i * 16][c4 + 2] = v.z;
    tile[r + i * 16][c4 + 3] = v.w;
  }
  __syncthreads();
#pragma unroll
  for (int i = 0; i < 4; ++i) {
    const int rr = r + i * 16;
    uint32_t lo = (uint32_t)f2bf(tile[c4 + 0][rr]) | ((uint32_t)f2bf(tile[c4 + 1][rr]) << 16);
    uint32_t hi = (uint32_t)f2bf(tile[c4 + 2][rr]) | ((uint32_t)f2bf(tile[c4 + 3][rr]) << 16);
    uint2 o; o.x = lo; o.y = hi;
    *reinterpret_cast<uint2*>(&WT[(size_t)(bx * 64 + rr) * DM + by * 64 + c4]) = o;
  }
}

// ---------------- x f32 -> bf16 ----------------
__global__ __launch_bounds__(256) void convert_x(
    const float* __restrict__ x, unsigned short* __restrict__ xb) {
  const int i = blockIdx.x * 256 + threadIdx.x;
  const float4 v = reinterpret_cast<const float4*>(x)[i];
  uint2 o;
  o.x = (uint32_t)f2bf(v.x) | ((uint32_t)f2bf(v.y) << 16);
  o.y = (uint32_t)f2bf(v.z) | ((uint32_t)f2bf(v.w) << 16);
  reinterpret_cast<uint2*>(xb)[i] = o;
}

// 0.125 (1/sqrt(64)) * log2(e): scores come out in base-2 logits
#define QSCALE 0.1803368801111204f

// -------- 256x256 BK=64 phase-interleaved GEMM (fused QKV), 8 waves -------
// Identical dataflow to the R8/R9-verified kernel (passed, bank-conflicts 0);
// sole change: __launch_bounds__(512, 1) so the allocator may use 256 VGPR
// (1 block/CU -> 2 waves/SIMD; waves x VGPR ~ 512/SIMD budget). This removes
// the 128-VGPR clamp that caused scratch spill (R7/R9: WRITE_SIZE ~0.3-0.7GB).
// 4 phases per K-tile: {ds_read subtile | issue 2 half-tile gload_lds (ph 0,1)
// | s_barrier | setprio + 16 MFMA | s_barrier}; tile boundary __syncthreads()
// (vmcnt(0) drains loads issued >=2 phases earlier).
__global__ __launch_bounds__(512, 1) void gemm_qkv2(
    const unsigned short* __restrict__ A, const unsigned short* __restrict__ B,
    const float* __restrict__ bq, const float* __restrict__ bk, const float* __restrict__ bv,
    unsigned short* __restrict__ out_q, unsigned short* __restrict__ out_k,
    unsigned short* __restrict__ out_v) {
  constexpr int NNT = 12;
  __shared__ unsigned short Abuf[2][256 * 64];
  __shared__ unsigned short Bbuf[2][256 * 64];

  const int tid = threadIdx.x;
  const int w = tid >> 6;
  const int lane = tid & 63;
  const int lrow = lane & 15;
  const int lhi = lane >> 4;
  const int wm = w >> 2;   // 0..1
  const int wn = w & 3;    // 0..3

  // XCD-chunked bijective swizzle (384 % 8 == 0)
  const int cpx = gridDim.x >> 3;
  const int bid = (blockIdx.x & 7) * cpx + (blockIdx.x >> 3);
  const int m0 = (bid / NNT) * 256;
  const int n0 = (bid % NNT) * 256;

  // staging: dest linear (lane*16B), source chunk pre-swizzled by row&7
  const int srow = w * 8 + (lane >> 3);
  const int sck = (lane & 7) ^ ((lane >> 3) & 7);

#define STAGE_RR(tt, bb, rr)                                                    \
  {                                                                             \
    const int kk = (tt) * 64;                                                   \
    gload16(&A[(size_t)(m0 + (rr) * 64 + srow) * DM + kk + sck * 8],            \
            (char*)&Abuf[bb][0] + ((rr) * 64 + w * 8) * 128);                   \
    gload16(&B[(size_t)(n0 + (rr) * 64 + srow) * DM + kk + sck * 8],            \
            (char*)&Bbuf[bb][0] + ((rr) * 64 + w * 8) * 128);                   \
  }

  const bool vswap = (n0 >= 2048);

  f32x4 acc[8][4];
#pragma unroll
  for (int m = 0; m < 8; ++m)
#pragma unroll
    for (int n = 0; n < 4; ++n) acc[m][n] = (f32x4){0.f, 0.f, 0.f, 0.f};

  STAGE_RR(0, 0, 0); STAGE_RR(0, 0, 1); STAGE_RR(0, 0, 2); STAGE_RR(0, 0, 3);
  __syncthreads();

  const int NK = DM / 64;  // 16 K-tiles
  for (int t = 0; t < NK; ++t) {
    const int bu = t & 1;
    bf16x8 bfr[4];
#pragma unroll
    for (int ph = 0; ph < 4; ++ph) {
      const int ks = ph >> 1, mh = ph & 1;
      if (mh == 0) {
#pragma unroll
        for (int n = 0; n < 4; ++n) {
          const int r = wn * 64 + n * 16 + lrow;
          bfr[n] = *reinterpret_cast<const bf16x8*>(
              &Bbuf[bu][r * 64 + (((ks * 4 + lhi) ^ (lane & 7)) << 3)]);
        }
      }
      bf16x8 af[4];
#pragma unroll
      for (int i = 0; i < 4; ++i) {
        const int r = wm * 128 + (mh * 4 + i) * 16 + lrow;
        af[i] = *reinterpret_cast<const bf16x8*>(
            &Abuf[bu][r * 64 + (((ks * 4 + lhi) ^ (lane & 7)) << 3)]);
      }
      if (ph < 2 && t + 1 < NK) {
        STAGE_RR(t + 1, bu ^ 1, 2 * ph);
        STAGE_RR(t + 1, bu ^ 1, 2 * ph + 1);
      }
      __builtin_amdgcn_s_barrier();
      __builtin_amdgcn_s_setprio(1);
      if (vswap) {
#pragma unroll
        for (int i = 0; i < 4; ++i)
#pragma unroll
          for (int n = 0; n < 4; ++n)
            acc[mh * 4 + i][n] =
                __builtin_amdgcn_mfma_f32_16x16x32_bf16(bfr[n], af[i], acc[mh * 4 + i][n], 0, 0, 0);
      } else {
#pragma unroll
        for (int i = 0; i < 4; ++i)
#pragma unroll
          for (int n = 0; n < 4; ++n)
            acc[mh * 4 + i][n] =
                __builtin_amdgcn_mfma_f32_16x16x32_bf16(af[i], bfr[n], acc[mh * 4 + i][n], 0, 0, 0);
      }
      __builtin_amdgcn_s_setprio(0);
      if (ph == 3) __syncthreads();          // vmcnt(0)+lgkm(0)+barrier: buf swap
      else __builtin_amdgcn_s_barrier();     // lockstep only (no hazard)
    }
  }
#undef STAGE_RR

  // ---- epilogue (identical to R7/R9-validated) ----
  if (!vswap) {
    const int isK = n0 >> 10;
    unsigned short* dst = isK ? out_k : out_q;
    const float* bp = isK ? bk : bq;
    const float sc = isK ? 1.f : QSCALE;
#pragma unroll
    for (int n = 0; n < 4; ++n) {
      const int col = (n0 & 1023) + wn * 64 + n * 16 + lrow;
      const float bb = bp[col];
      const int hh = col >> 6, dd = col & 63;
#pragma unroll
      for (int m = 0; m < 8; ++m) {
        const int rowb = m0 + wm * 128 + m * 16 + lhi * 4;
#pragma unroll
        for (int r = 0; r < 4; ++r) {
          const int mg = rowb + r;
          const int bidx = mg >> 11;
          const int nn = mg & 2047;
          dst[((size_t)(bidx * NHEAD + hh) * SEQL + nn) * HDIM + dd] =
              f2bf((acc[m][n][r] + bb) * sc);
        }
      }
    }
  } else {
    unsigned short* vo = out_v;
#pragma unroll
    for (int n = 0; n < 4; ++n) {
#pragma unroll
      for (int r = 0; r < 4; ++r) {
        const int ch = (n0 - 2048) + wn * 64 + n * 16 + lhi * 4 + r;
        const float bb = bv[ch];
        const int hh = ch >> 6, dd = ch & 63;
#pragma unroll
        for (int m = 0; m < 8; ++m) {
          const int seq = m0 + wm * 128 + m * 16 + lrow;
          const int bidx = seq >> 11;
          const int nn = seq & 2047;
          vo[((size_t)(bidx * NHEAD + hh) * HDIM + dd) * SEQL + nn] =
              f2bf(acc[m][n][r] + bb);
        }
      }
    }
  }
}

// ---------------- out-projection GEMM (proven R5 kernel, f32 out) ---------
__global__ __launch_bounds__(256) void gemm_out(
    const unsigned short* __restrict__ A, const unsigned short* __restrict__ BT,
    const float* __restrict__ bias, float* __restrict__ Cout) {
  __shared__ unsigned short As[128][64];
  __shared__ unsigned short Bs[128][64];
  const int tid = threadIdx.x;
  const int w = tid >> 6;
  const int lane = tid & 63;
  const int wm = w >> 1, wn = w & 1;
  const int m0 = (blockIdx.x >> 3) * 128;
  const int n0 = (blockIdx.x & 7) * 128;
  const int lrow = lane & 15;
  const int lk = (lane >> 4) * 8;
  const int sRow = lane >> 3;
  const int sCol = (lane & 7) * 8;

  f32x4 acc[4][4];
#pragma unroll
  for (int m = 0; m < 4; ++m)
#pragma unroll
    for (int n = 0; n < 4; ++n) acc[m][n] = (f32x4){0.f, 0.f, 0.f, 0.f};

  for (int k0 = 0; k0 < DM; k0 += 64) {
#pragma unroll
    for (int i = 0; i < 4; ++i) {
      const int rb = i * 32 + w * 8;
      gload16(&A[(size_t)(m0 + rb + sRow) * DM + k0 + sCol], &As[rb][0]);
    }
#pragma unroll
    for (int i = 0; i < 4; ++i) {
      const int rb = i * 32 + w * 8;
      gload16(&BT[(size_t)(n0 + rb + sRow) * DM + k0 + sCol], &Bs[rb][0]);
    }
    __syncthreads();
#pragma unroll
    for (int ks = 0; ks < 2; ++ks) {
      bf16x8 af[4], bfr[4];
#pragma unroll
      for (int m = 0; m < 4; ++m)
        af[m] = *reinterpret_cast<const bf16x8*>(&As[wm * 64 + m * 16 + lrow][ks * 32 + lk]);
#pragma unroll
      for (int n = 0; n < 4; ++n)
        bfr[n] = *reinterpret_cast<const bf16x8*>(&Bs[wn * 64 + n * 16 + lrow][ks * 32 + lk]);
#pragma unroll
      for (int m = 0; m < 4; ++m)
#pragma unroll
        for (int n = 0; n < 4; ++n)
          acc[m][n] = __builtin_amdgcn_mfma_f32_16x16x32_bf16(af[m], bfr[n], acc[m][n], 0, 0, 0);
    }
    __syncthreads();
  }

#pragma unroll
  for (int n = 0; n < 4; ++n) {
    const int col = n0 + wn * 64 + n * 16 + lrow;
    const float bb = bias[col];
#pragma unroll
    for (int m = 0; m < 4; ++m) {
      const int rowb = m0 + wm * 64 + m * 16 + (lane >> 4) * 4;
#pragma unroll
      for (int r = 0; r < 4; ++r) {
        Cout[(size_t)(rowb + r) * DM + col] = acc[m][n][r] + bb;
      }
    }
  }
}

// ---------------- flash attention: 8 warps x 32 q-rows, 2 KV-tiles/round ---
// (unchanged from R10 best)
__global__ __launch_bounds__(512) void attn_kernel(
    const unsigned short* __restrict__ q, const unsigned short* __restrict__ k,
    const unsigned short* __restrict__ vt, unsigned short* __restrict__ attn_out) {
  __shared__ unsigned short Ks[4][64 * 64];  // [set*2+half][kv][d] XOR-swizzled
  __shared__ unsigned short Vs[4][64 * 64];  // [set*2+half][d][kv] XOR-swizzled

  const int bid = blockIdx.x;
  const int l0 = (bid & 7) * 64 + (bid >> 3);
  const int bh = l0 >> 3;
  const int qt = l0 & 7;
  const int b = bh >> 4, h = bh & 15;

  const int tid = threadIdx.x;
  const int w = tid >> 6;
  const int lane = tid & 63;
  const int qv = lane & 31;
  const int hi = lane >> 5;
  const int qg0 = qt * 256 + w * 32;

  const unsigned short* qptr = q + (size_t)bh * SEQL * HDIM;
  const unsigned short* kptr = k + (size_t)bh * SEQL * HDIM;
  const unsigned short* vptr = vt + (size_t)bh * HDIM * SEQL;

  bf16x8 qb[4];
#pragma unroll
  for (int kc = 0; kc < 4; ++kc)
    qb[kc] = *reinterpret_cast<const bf16x8*>(&qptr[(qg0 + qv) * HDIM + kc * 16 + hi * 8]);

  bf16x8 ones;
#pragma unroll
  for (int i = 0; i < 8; ++i) ones[i] = (short)0x3F80;  // bf16 1.0

  f32x16 acc0 = zero16(), acc1 = zero16(), accL = zero16();

  const int x7 = qv & 7;
  int off[4];
#pragma unroll
  for (int i = 0; i < 4; ++i) off[i] = ((2 * i + hi) ^ x7) << 3;

  const int srow = tid >> 3;
  const int sslot = tid & 7;
  const int sdst = srow * 64 + ((sslot ^ (srow & 7)) << 3);

  uint4 rk0, rk1, rv0, rv1;
#define LOADT2(rr)                                                                       \
  {                                                                                      \
    rk0 = *reinterpret_cast<const uint4*>(&kptr[((rr) * 128 + srow) * HDIM + sslot * 8]);     \
    rk1 = *reinterpret_cast<const uint4*>(&kptr[((rr) * 128 + 64 + srow) * HDIM + sslot * 8]);\
    rv0 = *reinterpret_cast<const uint4*>(&vptr[srow * SEQL + (rr) * 128 + sslot * 8]);       \
    rv1 = *reinterpret_cast<const uint4*>(&vptr[srow * SEQL + (rr) * 128 + 64 + sslot * 8]);  \
  }

  LOADT2(0);
  const int NR = SEQL / 128;  // 16 rounds, 2 KV-tiles each
  for (int r = 0; r < NR; ++r) {
    const int s = (r & 1) << 1;
    *reinterpret_cast<uint4*>(&Ks[s][sdst]) = rk0;
    *reinterpret_cast<uint4*>(&Ks[s + 1][sdst]) = rk1;
    *reinterpret_cast<uint4*>(&Vs[s][sdst]) = rv0;
    *reinterpret_cast<uint4*>(&Vs[s + 1][sdst]) = rv1;
    __syncthreads();
    if (r + 1 < NR) LOADT2(r + 1);  // 8 loads in flight under a full round (T14)

#pragma unroll
    for (int half = 0; half < 2; ++half) {
      const int c = s + half;

      f32x16 p0 = zero16(), p1 = zero16();
      __builtin_amdgcn_s_setprio(1);
#pragma unroll
      for (int kc = 0; kc < 4; ++kc) {
        bf16x8 ka0 = *reinterpret_cast<const bf16x8*>(&Ks[c][qv * 64 + off[kc]]);
        bf16x8 ka1 = *reinterpret_cast<const bf16x8*>(&Ks[c][(32 + qv) * 64 + off[kc]]);
        p0 = __builtin_amdgcn_mfma_f32_32x32x16_bf16(ka0, qb[kc], p0, 0, 0, 0);
        p1 = __builtin_amdgcn_mfma_f32_32x32x16_bf16(ka1, qb[kc], p1, 0, 0, 0);
      }
      __builtin_amdgcn_s_setprio(0);

#pragma unroll
      for (int i = 0; i < 16; ++i) {
        p0[i] = exp2_fast(p0[i]);
        p1[i] = exp2_fast(p1[i]);
      }

      bf16x8 pa[4];
#pragma unroll
      for (int ks = 0; ks < 4; ++ks) {
        const int o = 8 * (ks & 1);
        uint32_t X1, X2, Y1, Y2;
        if (ks < 2) {
          X1 = pkbf(p0[o + 0], p0[o + 1]); X2 = pkbf(p0[o + 2], p0[o + 3]);
          Y1 = pkbf(p0[o + 4], p0[o + 5]); Y2 = pkbf(p0[o + 6], p0[o + 7]);
        } else {
          X1 = pkbf(p1[o + 0], p1[o + 1]); X2 = pkbf(p1[o + 2], p1[o + 3]);
          Y1 = pkbf(p1[o + 4], p1[o + 5]); Y2 = pkbf(p1[o + 6], p1[o + 7]);
        }
        asm("v_permlane32_swap_b32 %0, %1" : "+v"(X1), "+v"(Y1));
        asm("v_permlane32_swap_b32 %0, %1" : "+v"(X2), "+v"(Y2));
        union { uint32_t u[4]; bf16x8 v; } uu;
        uu.u[0] = X1; uu.u[1] = X2; uu.u[2] = Y1; uu.u[3] = Y2;
        pa[ks] = uu.v;
      }

      __builtin_amdgcn_s_setprio(1);
#pragma unroll
      for (int ks = 0; ks < 4; ++ks) {
        bf16x8 vb0 = *reinterpret_cast<const bf16x8*>(&Vs[c][qv * 64 + off[ks]]);
        bf16x8 vb1 = *reinterpret_cast<const bf16x8*>(&Vs[c][(32 + qv) * 64 + off[ks]]);
        acc0 = __builtin_amdgcn_mfma_f32_32x32x16_bf16(pa[ks], vb0, acc0, 0, 0, 0);
        acc1 = __builtin_amdgcn_mfma_f32_32x32x16_bf16(pa[ks], vb1, acc1, 0, 0, 0);
        accL = __builtin_amdgcn_mfma_f32_32x32x16_bf16(pa[ks], ones, accL, 0, 0, 0);
      }
      __builtin_amdgcn_s_setprio(0);
    }
  }
#undef LOADT2

#pragma unroll
  for (int rg = 0; rg < 16; ++rg) {
    const int crow = (rg & 3) + 8 * (rg >> 2) + 4 * hi;
    const float invl = 1.f / accL[rg];
    const int qg = qg0 + crow;
    const size_t base = ((size_t)(b * SEQL + qg) * NHEAD + h) * HDIM + qv;
    attn_out[base] = f2bf(acc0[rg] * invl);
    attn_out[base + 32] = f2bf(acc1[rg] * invl);
  }
}

extern "C" void kernel_launch(void* const* d_in, const int* in_sizes, int n_in,
                              void* d_out, int out_size, void* d_ws, size_t ws_size,
                              hipStream_t stream) {
  const float* x  = (const float*)d_in[0];
  const float* Wq = (const float*)d_in[1];
  const float* bq = (const float*)d_in[2];
  const float* Wk = (const float*)d_in[3];
  const float* bk = (const float*)d_in[4];
  const float* Wv = (const float*)d_in[5];
  const float* bv = (const float*)d_in[6];
  const float* Wo = (const float*)d_in[7];
  const float* bo = (const float*)d_in[8];

  char* ws = (char*)d_ws;
  unsigned short* wqT = (unsigned short*)(ws);            // [3072][1024] contiguous q,k,v
  unsigned short* wkT = wqT + 1024 * 1024;
  unsigned short* wvT = wkT + 1024 * 1024;
  unsigned short* woT = wvT + 1024 * 1024;
  unsigned short* xb   = (unsigned short*)(ws + (size_t)(8 << 20));
  unsigned short* attn = xb;  // reuse: x_bf16 dead after QKV projection
  unsigned short* qw   = (unsigned short*)(ws + (size_t)(24 << 20));
  unsigned short* kw   = (unsigned short*)(ws + (size_t)(40 << 20));
  unsigned short* vtw  = (unsigned short*)(ws + (size_t)(56 << 20));

  transpose_convert4<<<dim3(16, 16, 4), 256, 0, stream>>>(Wq, Wk, Wv, Wo, wqT, wkT, wvT, woT);
  convert_x<<<MTOT * DM / 4 / 256, 256, 0, stream>>>(x, xb);

  // fused QKV: M=8192 (32 m-tiles) x N=3072 (12 n-tiles) = 384 blocks
  gemm_qkv2<<<384, 512, 0, stream>>>(xb, wqT, bq, bk, bv, qw, kw, vtw);

  attn_kernel<<<512, 512, 0, stream>>>(qw, kw, vtw, attn);

  gemm_out<<<512, 256, 0, stream>>>(attn, woT, bo, (float*)d_out);
}

// Round 12
// 231.535 us; speedup vs baseline: 1.4595x; 1.4595x over previous
//
#include <hip/hip_runtime.h>
#include <hip/hip_bf16.h>
#include <stdint.h>

#define DM 1024
#define SEQL 2048
#define NBATCH 4
#define NHEAD 16
#define HDIM 64
#define MTOT (NBATCH * SEQL)  // 8192

using f32x4 = __attribute__((ext_vector_type(4))) float;
using f32x16 = __attribute__((ext_vector_type(16))) float;
using bf16x8 = __attribute__((ext_vector_type(8))) short;

static __device__ __forceinline__ unsigned short f2bf(float f) {
  union { float f; uint32_t u; } v; v.f = f;
  uint32_t u = v.u;
  return (unsigned short)((u + 0x7FFFu + ((u >> 16) & 1u)) >> 16);
}

static __device__ __forceinline__ float exp2_fast(float x) {
#if __has_builtin(__builtin_amdgcn_exp2f)
  return __builtin_amdgcn_exp2f(x);
#else
  float r;
  asm("v_exp_f32 %0, %1" : "=v"(r) : "v"(x));
  return r;
#endif
}

static __device__ __forceinline__ uint32_t pkbf(float lo, float hi) {
  float2 f; f.x = lo; f.y = hi;
  __hip_bfloat162 h = __float22bfloat162_rn(f);
  union { __hip_bfloat162 h; uint32_t u; } cv; cv.h = h;
  return cv.u;
}

static __device__ __forceinline__ f32x16 zero16() {
  f32x16 z;
#pragma unroll
  for (int i = 0; i < 16; ++i) z[i] = 0.f;
  return z;
}

static __device__ __forceinline__ void gload16(const void* g, void* l) {
  __builtin_amdgcn_global_load_lds(
      (const __attribute__((address_space(1))) unsigned int*)g,
      (__attribute__((address_space(3))) unsigned int*)l,
      16, 0, 0);
}

// ---------------- 4x weight transpose + f32->bf16 convert ----------------
__global__ __launch_bounds__(256) void transpose_convert4(
    const float* __restrict__ W0, const float* __restrict__ W1,
    const float* __restrict__ W2, const float* __restrict__ W3,
    unsigned short* __restrict__ T0, unsigned short* __restrict__ T1,
    unsigned short* __restrict__ T2, unsigned short* __restrict__ T3) {
  __shared__ float tile[64][65];
  const int z = blockIdx.z;
  const float* W = z == 0 ? W0 : z == 1 ? W1 : z == 2 ? W2 : W3;
  unsigned short* WT = z == 0 ? T0 : z == 1 ? T1 : z == 2 ? T2 : T3;
  const int bx = blockIdx.x;
  const int by = blockIdx.y;
  const int t = threadIdx.x;
  const int r = t >> 4;
  const int c4 = (t & 15) * 4;
#pragma unroll
  for (int i = 0; i < 4; ++i) {
    const float4 v = *reinterpret_cast<const float4*>(
        &W[(size_t)(by * 64 + r + i * 16) * DM + bx * 64 + c4]);
    tile[r + i * 16][c4 + 0] = v.x;
    tile[r + i * 16][c4 + 1] = v.y;
    tile[r + i * 16][c4 + 2] = v.z;
    tile[r + i * 16][c4 + 3] = v.w;
  }
  __syncthreads();
#pragma unroll
  for (int i = 0; i < 4; ++i) {
    const int rr = r + i * 16;
    uint32_t lo = (uint32_t)f2bf(tile[c4 + 0][rr]) | ((uint32_t)f2bf(tile[c4 + 1][rr]) << 16);
    uint32_t hi = (uint32_t)f2bf(tile[c4 + 2][rr]) | ((uint32_t)f2bf(tile[c4 + 3][rr]) << 16);
    uint2 o; o.x = lo; o.y = hi;
    *reinterpret_cast<uint2*>(&WT[(size_t)(bx * 64 + rr) * DM + by * 64 + c4]) = o;
  }
}

// ---------------- x f32 -> bf16 ----------------
__global__ __launch_bounds__(256) void convert_x(
    const float* __restrict__ x, unsigned short* __restrict__ xb) {
  const int i = blockIdx.x * 256 + threadIdx.x;
  const float4 v = reinterpret_cast<const float4*>(x)[i];
  uint2 o;
  o.x = (uint32_t)f2bf(v.x) | ((uint32_t)f2bf(v.y) << 16);
  o.y = (uint32_t)f2bf(v.z) | ((uint32_t)f2bf(v.w) << 16);
  reinterpret_cast<uint2*>(xb)[i] = o;
}

// 0.125 (1/sqrt(64)) * log2(e): scores come out in base-2 logits
#define QSCALE 0.1803368801111204f

// ---------------- fused QKV projection GEMM v3 -----------------------------
// 128x128 tile, 4 waves, BK=64. A staged to XOR-swizzled dbuf LDS (one
// barrier per K-tile); B fragments read DIRECTLY from global (L2/L3-hot
// weights) — removes half the LDS traffic and all B staging. Mode = n0>>10:
// 0=Q (scaled) 1=K 2=V; mode 2 uses operand-swapped MFMA (R7-validated) to
// produce the transposed tile in-register -> coalesced [BH][64][N] store.
__global__ __launch_bounds__(256) void gemm_qkv(
    const unsigned short* __restrict__ A, const unsigned short* __restrict__ BT,
    const float* __restrict__ bq, const float* __restrict__ bk, const float* __restrict__ bv,
    unsigned short* __restrict__ qo, unsigned short* __restrict__ ko,
    unsigned short* __restrict__ vo) {
  __shared__ unsigned short As[2][128 * 64];
  const int tid = threadIdx.x;
  const int w = tid >> 6;
  const int lane = tid & 63;
  const int wm = w >> 1, wn = w & 1;
  const int m0 = blockIdx.y * 128;
  const int n0 = blockIdx.x * 128;
  const int mode = n0 >> 10;
  const int lrow = lane & 15;
  const int lhi = lane >> 4;
  const int sRow = lane >> 3;
  const int sColSwz = (((lane & 7) ^ ((lane >> 3) & 7))) * 8;  // involution src swz

#define STAGE_A(tt, bb)                                                        \
  {                                                                            \
    const int kk = (tt) * 64;                                                  \
    _Pragma("unroll") for (int i = 0; i < 4; ++i) {                            \
      const int rb = i * 32 + w * 8;                                           \
      gload16(&A[(size_t)(m0 + rb + sRow) * DM + kk + sColSwz], &As[bb][rb * 64]); \
    }                                                                          \
  }

  f32x4 acc[4][4];
#pragma unroll
  for (int m = 0; m < 4; ++m)
#pragma unroll
    for (int n = 0; n < 4; ++n) acc[m][n] = (f32x4){0.f, 0.f, 0.f, 0.f};

  STAGE_A(0, 0);
  __syncthreads();

  const int NK = DM / 64;  // 16
  for (int t = 0; t < NK; ++t) {
    const int bu = t & 1;
    if (t + 1 < NK) STAGE_A(t + 1, bu ^ 1);  // lands under this tile's compute
    const int k0 = t * 64;
#pragma unroll
    for (int ks = 0; ks < 2; ++ks) {
      bf16x8 af[4], bfr[4];
#pragma unroll
      for (int m = 0; m < 4; ++m) {
        const int r = wm * 64 + m * 16 + lrow;
        af[m] = *reinterpret_cast<const bf16x8*>(
            &As[bu][r * 64 + (((ks * 4 + lhi) ^ (lrow & 7)) << 3)]);
      }
#pragma unroll
      for (int n = 0; n < 4; ++n)
        bfr[n] = *reinterpret_cast<const bf16x8*>(
            &BT[(size_t)(n0 + wn * 64 + n * 16 + lrow) * DM + k0 + ks * 32 + lhi * 8]);

      __builtin_amdgcn_s_setprio(1);
      if (mode == 2) {
#pragma unroll
        for (int n = 0; n < 4; ++n)
#pragma unroll
          for (int m = 0; m < 4; ++m)
            acc[n][m] = __builtin_amdgcn_mfma_f32_16x16x32_bf16(bfr[n], af[m], acc[n][m], 0, 0, 0);
      } else {
#pragma unroll
        for (int m = 0; m < 4; ++m)
#pragma unroll
          for (int n = 0; n < 4; ++n)
            acc[m][n] = __builtin_amdgcn_mfma_f32_16x16x32_bf16(af[m], bfr[n], acc[m][n], 0, 0, 0);
      }
      __builtin_amdgcn_s_setprio(0);
    }
    __syncthreads();  // vmcnt(0)+lgkm(0)+barrier: next buffer landed, safe swap
  }
#undef STAGE_A

  if (mode < 2) {
    const bool isK = (mode == 1);
    unsigned short* dst = isK ? ko : qo;
    const float* bp = isK ? bk : bq;
    const float sc = isK ? 1.f : QSCALE;
#pragma unroll
    for (int n = 0; n < 4; ++n) {
      const int col = (n0 & 1023) + wn * 64 + n * 16 + lrow;
      const float bb = bp[col];
      const int hh = col >> 6, dd = col & 63;
#pragma unroll
      for (int m = 0; m < 4; ++m) {
        const int rowb = m0 + wm * 64 + m * 16 + lhi * 4;
#pragma unroll
        for (int r = 0; r < 4; ++r) {
          const int mg = rowb + r;
          const int bidx = mg >> 11;
          const int nn = mg & 2047;
          dst[((size_t)(bidx * NHEAD + hh) * SEQL + nn) * HDIM + dd] =
              f2bf((acc[m][n][r] + bb) * sc);
        }
      }
    }
  } else {
    // transposed tile (operand swap): acc[n][m] rows = V channels, cols = seq
#pragma unroll
    for (int n = 0; n < 4; ++n) {
#pragma unroll
      for (int r = 0; r < 4; ++r) {
        const int dv = (n0 - 2048) + wn * 64 + n * 16 + lhi * 4 + r;
        const float bb = bv[dv];
        const int hh = dv >> 6, dd = dv & 63;
#pragma unroll
        for (int m = 0; m < 4; ++m) {
          const int seq = m0 + wm * 64 + m * 16 + lrow;
          const int bidx = seq >> 11;
          const int nn = seq & 2047;
          vo[((size_t)(bidx * NHEAD + hh) * HDIM + dd) * SEQL + nn] =
              f2bf(acc[n][m][r] + bb);
        }
      }
    }
  }
}

// ---------------- out-projection GEMM (proven R5 kernel, f32 out) ---------
__global__ __launch_bounds__(256) void gemm_out(
    const unsigned short* __restrict__ A, const unsigned short* __restrict__ BT,
    const float* __restrict__ bias, float* __restrict__ Cout) {
  __shared__ unsigned short As[128][64];
  __shared__ unsigned short Bs[128][64];
  const int tid = threadIdx.x;
  const int w = tid >> 6;
  const int lane = tid & 63;
  const int wm = w >> 1, wn = w & 1;
  const int m0 = (blockIdx.x >> 3) * 128;
  const int n0 = (blockIdx.x & 7) * 128;
  const int lrow = lane & 15;
  const int lk = (lane >> 4) * 8;
  const int sRow = lane >> 3;
  const int sCol = (lane & 7) * 8;

  f32x4 acc[4][4];
#pragma unroll
  for (int m = 0; m < 4; ++m)
#pragma unroll
    for (int n = 0; n < 4; ++n) acc[m][n] = (f32x4){0.f, 0.f, 0.f, 0.f};

  for (int k0 = 0; k0 < DM; k0 += 64) {
#pragma unroll
    for (int i = 0; i < 4; ++i) {
      const int rb = i * 32 + w * 8;
      gload16(&A[(size_t)(m0 + rb + sRow) * DM + k0 + sCol], &As[rb][0]);
    }
#pragma unroll
    for (int i = 0; i < 4; ++i) {
      const int rb = i * 32 + w * 8;
      gload16(&BT[(size_t)(n0 + rb + sRow) * DM + k0 + sCol], &Bs[rb][0]);
    }
    __syncthreads();
#pragma unroll
    for (int ks = 0; ks < 2; ++ks) {
      bf16x8 af[4], bfr[4];
#pragma unroll
      for (int m = 0; m < 4; ++m)
        af[m] = *reinterpret_cast<const bf16x8*>(&As[wm * 64 + m * 16 + lrow][ks * 32 + lk]);
#pragma unroll
      for (int n = 0; n < 4; ++n)
        bfr[n] = *reinterpret_cast<const bf16x8*>(&Bs[wn * 64 + n * 16 + lrow][ks * 32 + lk]);
#pragma unroll
      for (int m = 0; m < 4; ++m)
#pragma unroll
        for (int n = 0; n < 4; ++n)
          acc[m][n] = __builtin_amdgcn_mfma_f32_16x16x32_bf16(af[m], bfr[n], acc[m][n], 0, 0, 0);
    }
    __syncthreads();
  }

#pragma unroll
  for (int n = 0; n < 4; ++n) {
    const int col = n0 + wn * 64 + n * 16 + lrow;
    const float bb = bias[col];
#pragma unroll
    for (int m = 0; m < 4; ++m) {
      const int rowb = m0 + wm * 64 + m * 16 + (lane >> 4) * 4;
#pragma unroll
      for (int r = 0; r < 4; ++r) {
        Cout[(size_t)(rowb + r) * DM + col] = acc[m][n][r] + bb;
      }
    }
  }
}

// ---------------- flash attention: 8 warps x 32 q-rows, 2 KV-tiles/round ---
// (unchanged from R10 best)
__global__ __launch_bounds__(512) void attn_kernel(
    const unsigned short* __restrict__ q, const unsigned short* __restrict__ k,
    const unsigned short* __restrict__ vt, unsigned short* __restrict__ attn_out) {
  __shared__ unsigned short Ks[4][64 * 64];  // [set*2+half][kv][d] XOR-swizzled
  __shared__ unsigned short Vs[4][64 * 64];  // [set*2+half][d][kv] XOR-swizzled

  const int bid = blockIdx.x;
  const int l0 = (bid & 7) * 64 + (bid >> 3);
  const int bh = l0 >> 3;
  const int qt = l0 & 7;
  const int b = bh >> 4, h = bh & 15;

  const int tid = threadIdx.x;
  const int w = tid >> 6;
  const int lane = tid & 63;
  const int qv = lane & 31;
  const int hi = lane >> 5;
  const int qg0 = qt * 256 + w * 32;

  const unsigned short* qptr = q + (size_t)bh * SEQL * HDIM;
  const unsigned short* kptr = k + (size_t)bh * SEQL * HDIM;
  const unsigned short* vptr = vt + (size_t)bh * HDIM * SEQL;

  bf16x8 qb[4];
#pragma unroll
  for (int kc = 0; kc < 4; ++kc)
    qb[kc] = *reinterpret_cast<const bf16x8*>(&qptr[(qg0 + qv) * HDIM + kc * 16 + hi * 8]);

  bf16x8 ones;
#pragma unroll
  for (int i = 0; i < 8; ++i) ones[i] = (short)0x3F80;  // bf16 1.0

  f32x16 acc0 = zero16(), acc1 = zero16(), accL = zero16();

  const int x7 = qv & 7;
  int off[4];
#pragma unroll
  for (int i = 0; i < 4; ++i) off[i] = ((2 * i + hi) ^ x7) << 3;

  const int srow = tid >> 3;
  const int sslot = tid & 7;
  const int sdst = srow * 64 + ((sslot ^ (srow & 7)) << 3);

  uint4 rk0, rk1, rv0, rv1;
#define LOADT2(rr)                                                                       \
  {                                                                                      \
    rk0 = *reinterpret_cast<const uint4*>(&kptr[((rr) * 128 + srow) * HDIM + sslot * 8]);     \
    rk1 = *reinterpret_cast<const uint4*>(&kptr[((rr) * 128 + 64 + srow) * HDIM + sslot * 8]);\
    rv0 = *reinterpret_cast<const uint4*>(&vptr[srow * SEQL + (rr) * 128 + sslot * 8]);       \
    rv1 = *reinterpret_cast<const uint4*>(&vptr[srow * SEQL + (rr) * 128 + 64 + sslot * 8]);  \
  }

  LOADT2(0);
  const int NR = SEQL / 128;  // 16 rounds, 2 KV-tiles each
  for (int r = 0; r < NR; ++r) {
    const int s = (r & 1) << 1;
    *reinterpret_cast<uint4*>(&Ks[s][sdst]) = rk0;
    *reinterpret_cast<uint4*>(&Ks[s + 1][sdst]) = rk1;
    *reinterpret_cast<uint4*>(&Vs[s][sdst]) = rv0;
    *reinterpret_cast<uint4*>(&Vs[s + 1][sdst]) = rv1;
    __syncthreads();
    if (r + 1 < NR) LOADT2(r + 1);  // 8 loads in flight under a full round (T14)

#pragma unroll
    for (int half = 0; half < 2; ++half) {
      const int c = s + half;

      f32x16 p0 = zero16(), p1 = zero16();
      __builtin_amdgcn_s_setprio(1);
#pragma unroll
      for (int kc = 0; kc < 4; ++kc) {
        bf16x8 ka0 = *reinterpret_cast<const bf16x8*>(&Ks[c][qv * 64 + off[kc]]);
        bf16x8 ka1 = *reinterpret_cast<const bf16x8*>(&Ks[c][(32 + qv) * 64 + off[kc]]);
        p0 = __builtin_amdgcn_mfma_f32_32x32x16_bf16(ka0, qb[kc], p0, 0, 0, 0);
        p1 = __builtin_amdgcn_mfma_f32_32x32x16_bf16(ka1, qb[kc], p1, 0, 0, 0);
      }
      __builtin_amdgcn_s_setprio(0);

#pragma unroll
      for (int i = 0; i < 16; ++i) {
        p0[i] = exp2_fast(p0[i]);
        p1[i] = exp2_fast(p1[i]);
      }

      bf16x8 pa[4];
#pragma unroll
      for (int ks = 0; ks < 4; ++ks) {
        const int o = 8 * (ks & 1);
        uint32_t X1, X2, Y1, Y2;
        if (ks < 2) {
          X1 = pkbf(p0[o + 0], p0[o + 1]); X2 = pkbf(p0[o + 2], p0[o + 3]);
          Y1 = pkbf(p0[o + 4], p0[o + 5]); Y2 = pkbf(p0[o + 6], p0[o + 7]);
        } else {
          X1 = pkbf(p1[o + 0], p1[o + 1]); X2 = pkbf(p1[o + 2], p1[o + 3]);
          Y1 = pkbf(p1[o + 4], p1[o + 5]); Y2 = pkbf(p1[o + 6], p1[o + 7]);
        }
        asm("v_permlane32_swap_b32 %0, %1" : "+v"(X1), "+v"(Y1));
        asm("v_permlane32_swap_b32 %0, %1" : "+v"(X2), "+v"(Y2));
        union { uint32_t u[4]; bf16x8 v; } uu;
        uu.u[0] = X1; uu.u[1] = X2; uu.u[2] = Y1; uu.u[3] = Y2;
        pa[ks] = uu.v;
      }

      __builtin_amdgcn_s_setprio(1);
#pragma unroll
      for (int ks = 0; ks < 4; ++ks) {
        bf16x8 vb0 = *reinterpret_cast<const bf16x8*>(&Vs[c][qv * 64 + off[ks]]);
        bf16x8 vb1 = *reinterpret_cast<const bf16x8*>(&Vs[c][(32 + qv) * 64 + off[ks]]);
        acc0 = __builtin_amdgcn_mfma_f32_32x32x16_bf16(pa[ks], vb0, acc0, 0, 0, 0);
        acc1 = __builtin_amdgcn_mfma_f32_32x32x16_bf16(pa[ks], vb1, acc1, 0, 0, 0);
        accL = __builtin_amdgcn_mfma_f32_32x32x16_bf16(pa[ks], ones, accL, 0, 0, 0);
      }
      __builtin_amdgcn_s_setprio(0);
    }
  }
#undef LOADT2

#pragma unroll
  for (int rg = 0; rg < 16; ++rg) {
    const int crow = (rg & 3) + 8 * (rg >> 2) + 4 * hi;
    const float invl = 1.f / accL[rg];
    const int qg = qg0 + crow;
    const size_t base = ((size_t)(b * SEQL + qg) * NHEAD + h) * HDIM + qv;
    attn_out[base] = f2bf(acc0[rg] * invl);
    attn_out[base + 32] = f2bf(acc1[rg] * invl);
  }
}

extern "C" void kernel_launch(void* const* d_in, const int* in_sizes, int n_in,
                              void* d_out, int out_size, void* d_ws, size_t ws_size,
                              hipStream_t stream) {
  const float* x  = (const float*)d_in[0];
  const float* Wq = (const float*)d_in[1];
  const float* bq = (const float*)d_in[2];
  const float* Wk = (const float*)d_in[3];
  const float* bk = (const float*)d_in[4];
  const float* Wv = (const float*)d_in[5];
  const float* bv = (const float*)d_in[6];
  const float* Wo = (const float*)d_in[7];
  const float* bo = (const float*)d_in[8];

  char* ws = (char*)d_ws;
  unsigned short* wqT = (unsigned short*)(ws);            // [3072][1024] contiguous q,k,v
  unsigned short* wkT = wqT + 1024 * 1024;
  unsigned short* wvT = wkT + 1024 * 1024;
  unsigned short* woT = wvT + 1024 * 1024;
  unsigned short* xb   = (unsigned short*)(ws + (size_t)(8 << 20));
  unsigned short* attn = xb;  // reuse: x_bf16 dead after QKV projection
  unsigned short* qw   = (unsigned short*)(ws + (size_t)(24 << 20));
  unsigned short* kw   = (unsigned short*)(ws + (size_t)(40 << 20));
  unsigned short* vtw  = (unsigned short*)(ws + (size_t)(56 << 20));

  transpose_convert4<<<dim3(16, 16, 4), 256, 0, stream>>>(Wq, Wk, Wv, Wo, wqT, wkT, wvT, woT);
  convert_x<<<MTOT * DM / 4 / 256, 256, 0, stream>>>(x, xb);

  gemm_qkv<<<dim3(24, 64), 256, 0, stream>>>(xb, wqT, bq, bk, bv, qw, kw, vtw);

  attn_kernel<<<512, 512, 0, stream>>>(qw, kw, vtw, attn);

  gemm_out<<<512, 256, 0, stream>>>(attn, woT, bo, (float*)d_out);
}

// Round 13
// 191.372 us; speedup vs baseline: 1.7658x; 1.2099x over previous
//
#include <hip/hip_runtime.h>
#include <hip/hip_bf16.h>
#include <stdint.h>

#define DM 1024
#define SEQL 2048
#define NBATCH 4
#define NHEAD 16
#define HDIM 64
#define MTOT (NBATCH * SEQL)  // 8192

using f32x4 = __attribute__((ext_vector_type(4))) float;
using f32x16 = __attribute__((ext_vector_type(16))) float;
using bf16x8 = __attribute__((ext_vector_type(8))) short;

static __device__ __forceinline__ unsigned short f2bf(float f) {
  union { float f; uint32_t u; } v; v.f = f;
  uint32_t u = v.u;
  return (unsigned short)((u + 0x7FFFu + ((u >> 16) & 1u)) >> 16);
}

static __device__ __forceinline__ float exp2_fast(float x) {
#if __has_builtin(__builtin_amdgcn_exp2f)
  return __builtin_amdgcn_exp2f(x);
#else
  float r;
  asm("v_exp_f32 %0, %1" : "=v"(r) : "v"(x));
  return r;
#endif
}

static __device__ __forceinline__ uint32_t pkbf(float lo, float hi) {
  float2 f; f.x = lo; f.y = hi;
  __hip_bfloat162 h = __float22bfloat162_rn(f);
  union { __hip_bfloat162 h; uint32_t u; } cv; cv.h = h;
  return cv.u;
}

static __device__ __forceinline__ f32x16 zero16() {
  f32x16 z;
#pragma unroll
  for (int i = 0; i < 16; ++i) z[i] = 0.f;
  return z;
}

static __device__ __forceinline__ void gload16(const void* g, void* l) {
  __builtin_amdgcn_global_load_lds(
      (const __attribute__((address_space(1))) unsigned int*)g,
      (__attribute__((address_space(3))) unsigned int*)l,
      16, 0, 0);
}

// ---------------- 4x weight transpose + f32->bf16 convert ----------------
__global__ __launch_bounds__(256) void transpose_convert4(
    const float* __restrict__ W0, const float* __restrict__ W1,
    const float* __restrict__ W2, const float* __restrict__ W3,
    unsigned short* __restrict__ T0, unsigned short* __restrict__ T1,
    unsigned short* __restrict__ T2, unsigned short* __restrict__ T3) {
  __shared__ float tile[64][65];
  const int z = blockIdx.z;
  const float* W = z == 0 ? W0 : z == 1 ? W1 : z == 2 ? W2 : W3;
  unsigned short* WT = z == 0 ? T0 : z == 1 ? T1 : z == 2 ? T2 : T3;
  const int bx = blockIdx.x;
  const int by = blockIdx.y;
  const int t = threadIdx.x;
  const int r = t >> 4;
  const int c4 = (t & 15) * 4;
#pragma unroll
  for (int i = 0; i < 4; ++i) {
    const float4 v = *reinterpret_cast<const float4*>(
        &W[(size_t)(by * 64 + r + i * 16) * DM + bx * 64 + c4]);
    tile[r + i * 16][c4 + 0] = v.x;
    tile[r + i * 16][c4 + 1] = v.y;
    tile[r + i * 16][c4 + 2] = v.z;
    tile[r + i * 16][c4 + 3] = v.w;
  }
  __syncthreads();
#pragma unroll
  for (int i = 0; i < 4; ++i) {
    const int rr = r + i * 16;
    uint32_t lo = (uint32_t)f2bf(tile[c4 + 0][rr]) | ((uint32_t)f2bf(tile[c4 + 1][rr]) << 16);
    uint32_t hi = (uint32_t)f2bf(tile[c4 + 2][rr]) | ((uint32_t)f2bf(tile[c4 + 3][rr]) << 16);
    uint2 o; o.x = lo; o.y = hi;
    *reinterpret_cast<uint2*>(&WT[(size_t)(bx * 64 + rr) * DM + by * 64 + c4]) = o;
  }
}

// ---------------- x f32 -> bf16 ----------------
__global__ __launch_bounds__(256) void convert_x(
    const float* __restrict__ x, unsigned short* __restrict__ xb) {
  const int i = blockIdx.x * 256 + threadIdx.x;
  const float4 v = reinterpret_cast<const float4*>(x)[i];
  uint2 o;
  o.x = (uint32_t)f2bf(v.x) | ((uint32_t)f2bf(v.y) << 16);
  o.y = (uint32_t)f2bf(v.z) | ((uint32_t)f2bf(v.w) << 16);
  reinterpret_cast<uint2*>(xb)[i] = o;
}

// 0.125 (1/sqrt(64)) * log2(e): scores come out in base-2 logits
#define QSCALE 0.1803368801111204f

// ---------------- fused QKV projection GEMM (R5 structure + swizzle) ------
// C[8192][3072] = A * BT^T. Block-uniform mode = n0>>10: 0=Q 1=K 2=V.
// Mode 2 swaps the LDS staging destinations so the identical inner loop
// computes the TRANSPOSED tile in-register; V^T store is coalesced.
// NEW vs R5 (one variable): LDS XOR-swizzle on BOTH tiles — global source
// column pre-swizzled ((l&7)^((l>>3)&7))*8 with linear gload_lds dest, and
// fragment reads use slot (ks*4+lhi)^(lrow&7). R12 measured 0 conflicts for
// exactly this access pattern (vs 1.89e7 unswizzled = ~35% of runtime).
__global__ __launch_bounds__(256) void gemm_qkv(
    const unsigned short* __restrict__ A, const unsigned short* __restrict__ BT,
    const float* __restrict__ bq, const float* __restrict__ bk, const float* __restrict__ bv,
    unsigned short* __restrict__ qo, unsigned short* __restrict__ ko,
    unsigned short* __restrict__ vo) {
  __shared__ unsigned short As[128][64];
  __shared__ unsigned short Bs[128][64];
  const int tid = threadIdx.x;
  const int w = tid >> 6;
  const int lane = tid & 63;
  const int wm = w >> 1, wn = w & 1;
  const int m0 = blockIdx.y * 128;
  const int n0 = blockIdx.x * 128;
  const int mode = n0 >> 10;
  const int lrow = lane & 15;
  const int lhi = lane >> 4;
  const int sRow = lane >> 3;
  const int sColSwz = ((lane & 7) ^ ((lane >> 3) & 7)) * 8;  // src pre-swizzle
  const int x7 = lrow & 7;

  unsigned short* dstA = (mode == 2) ? &Bs[0][0] : &As[0][0];
  unsigned short* dstB = (mode == 2) ? &As[0][0] : &Bs[0][0];

  f32x4 acc[4][4];
#pragma unroll
  for (int m = 0; m < 4; ++m)
#pragma unroll
    for (int n = 0; n < 4; ++n) acc[m][n] = (f32x4){0.f, 0.f, 0.f, 0.f};

  for (int k0 = 0; k0 < DM; k0 += 64) {
#pragma unroll
    for (int i = 0; i < 4; ++i) {
      const int rb = i * 32 + w * 8;
      gload16(&A[(size_t)(m0 + rb + sRow) * DM + k0 + sColSwz], dstA + rb * 64);
    }
#pragma unroll
    for (int i = 0; i < 4; ++i) {
      const int rb = i * 32 + w * 8;
      gload16(&BT[(size_t)(n0 + rb + sRow) * DM + k0 + sColSwz], dstB + rb * 64);
    }
    __syncthreads();
#pragma unroll
    for (int ks = 0; ks < 2; ++ks) {
      const int slot = ((ks * 4 + lhi) ^ x7) << 3;
      bf16x8 af[4], bfr[4];
#pragma unroll
      for (int m = 0; m < 4; ++m)
        af[m] = *reinterpret_cast<const bf16x8*>(&As[wm * 64 + m * 16 + lrow][slot]);
#pragma unroll
      for (int n = 0; n < 4; ++n)
        bfr[n] = *reinterpret_cast<const bf16x8*>(&Bs[wn * 64 + n * 16 + lrow][slot]);
#pragma unroll
      for (int m = 0; m < 4; ++m)
#pragma unroll
        for (int n = 0; n < 4; ++n)
          acc[m][n] = __builtin_amdgcn_mfma_f32_16x16x32_bf16(af[m], bfr[n], acc[m][n], 0, 0, 0);
    }
    __syncthreads();
  }

  if (mode < 2) {
    const bool isK = (mode == 1);
    unsigned short* dst = isK ? ko : qo;
    const float* bp = isK ? bk : bq;
    const float sc = isK ? 1.f : QSCALE;
#pragma unroll
    for (int n = 0; n < 4; ++n) {
      const int col = (n0 & 1023) + wn * 64 + n * 16 + lrow;
      const float bb = bp[col];
      const int hh = col >> 6, dd = col & 63;
#pragma unroll
      for (int m = 0; m < 4; ++m) {
        const int rowb = m0 + wm * 64 + m * 16 + lhi * 4;
#pragma unroll
        for (int r = 0; r < 4; ++r) {
          const int mg = rowb + r;
          const int bidx = mg >> 11;
          const int nn = mg & 2047;
          dst[((size_t)(bidx * NHEAD + hh) * SEQL + nn) * HDIM + dd] =
              f2bf((acc[m][n][r] + bb) * sc);
        }
      }
    }
  } else {
    // transposed tile: acc rows = V channels, cols = sequence
#pragma unroll
    for (int m = 0; m < 4; ++m) {
#pragma unroll
      for (int r = 0; r < 4; ++r) {
        const int dv = (n0 - 2048) + wm * 64 + m * 16 + lhi * 4 + r;
        const float bb = bv[dv];
        const int hh = dv >> 6, dd = dv & 63;
#pragma unroll
        for (int n = 0; n < 4; ++n) {
          const int seq = m0 + wn * 64 + n * 16 + lrow;
          const int bidx = seq >> 11;
          const int nn = seq & 2047;
          vo[((size_t)(bidx * NHEAD + hh) * HDIM + dd) * SEQL + nn] =
              f2bf(acc[m][n][r] + bb);
        }
      }
    }
  }
}

// ---------------- out-projection GEMM (R5 structure + swizzle, f32 out) ---
__global__ __launch_bounds__(256) void gemm_out(
    const unsigned short* __restrict__ A, const unsigned short* __restrict__ BT,
    const float* __restrict__ bias, float* __restrict__ Cout) {
  __shared__ unsigned short As[128][64];
  __shared__ unsigned short Bs[128][64];
  const int tid = threadIdx.x;
  const int w = tid >> 6;
  const int lane = tid & 63;
  const int wm = w >> 1, wn = w & 1;
  const int m0 = (blockIdx.x >> 3) * 128;
  const int n0 = (blockIdx.x & 7) * 128;
  const int lrow = lane & 15;
  const int lhi = lane >> 4;
  const int sRow = lane >> 3;
  const int sColSwz = ((lane & 7) ^ ((lane >> 3) & 7)) * 8;
  const int x7 = lrow & 7;

  f32x4 acc[4][4];
#pragma unroll
  for (int m = 0; m < 4; ++m)
#pragma unroll
    for (int n = 0; n < 4; ++n) acc[m][n] = (f32x4){0.f, 0.f, 0.f, 0.f};

  for (int k0 = 0; k0 < DM; k0 += 64) {
#pragma unroll
    for (int i = 0; i < 4; ++i) {
      const int rb = i * 32 + w * 8;
      gload16(&A[(size_t)(m0 + rb + sRow) * DM + k0 + sColSwz], &As[rb][0]);
    }
#pragma unroll
    for (int i = 0; i < 4; ++i) {
      const int rb = i * 32 + w * 8;
      gload16(&BT[(size_t)(n0 + rb + sRow) * DM + k0 + sColSwz], &Bs[rb][0]);
    }
    __syncthreads();
#pragma unroll
    for (int ks = 0; ks < 2; ++ks) {
      const int slot = ((ks * 4 + lhi) ^ x7) << 3;
      bf16x8 af[4], bfr[4];
#pragma unroll
      for (int m = 0; m < 4; ++m)
        af[m] = *reinterpret_cast<const bf16x8*>(&As[wm * 64 + m * 16 + lrow][slot]);
#pragma unroll
      for (int n = 0; n < 4; ++n)
        bfr[n] = *reinterpret_cast<const bf16x8*>(&Bs[wn * 64 + n * 16 + lrow][slot]);
#pragma unroll
      for (int m = 0; m < 4; ++m)
#pragma unroll
        for (int n = 0; n < 4; ++n)
          acc[m][n] = __builtin_amdgcn_mfma_f32_16x16x32_bf16(af[m], bfr[n], acc[m][n], 0, 0, 0);
    }
    __syncthreads();
  }

#pragma unroll
  for (int n = 0; n < 4; ++n) {
    const int col = n0 + wn * 64 + n * 16 + lrow;
    const float bb = bias[col];
#pragma unroll
    for (int m = 0; m < 4; ++m) {
      const int rowb = m0 + wm * 64 + m * 16 + lhi * 4;
#pragma unroll
      for (int r = 0; r < 4; ++r) {
        Cout[(size_t)(rowb + r) * DM + col] = acc[m][n][r] + bb;
      }
    }
  }
}

// ---------------- flash attention: 8 warps x 32 q-rows, 2 KV-tiles/round ---
// (unchanged from R10 best)
__global__ __launch_bounds__(512) void attn_kernel(
    const unsigned short* __restrict__ q, const unsigned short* __restrict__ k,
    const unsigned short* __restrict__ vt, unsigned short* __restrict__ attn_out) {
  __shared__ unsigned short Ks[4][64 * 64];  // [set*2+half][kv][d] XOR-swizzled
  __shared__ unsigned short Vs[4][64 * 64];  // [set*2+half][d][kv] XOR-swizzled

  const int bid = blockIdx.x;
  const int l0 = (bid & 7) * 64 + (bid >> 3);
  const int bh = l0 >> 3;
  const int qt = l0 & 7;
  const int b = bh >> 4, h = bh & 15;

  const int tid = threadIdx.x;
  const int w = tid >> 6;
  const int lane = tid & 63;
  const int qv = lane & 31;
  const int hi = lane >> 5;
  const int qg0 = qt * 256 + w * 32;

  const unsigned short* qptr = q + (size_t)bh * SEQL * HDIM;
  const unsigned short* kptr = k + (size_t)bh * SEQL * HDIM;
  const unsigned short* vptr = vt + (size_t)bh * HDIM * SEQL;

  bf16x8 qb[4];
#pragma unroll
  for (int kc = 0; kc < 4; ++kc)
    qb[kc] = *reinterpret_cast<const bf16x8*>(&qptr[(qg0 + qv) * HDIM + kc * 16 + hi * 8]);

  bf16x8 ones;
#pragma unroll
  for (int i = 0; i < 8; ++i) ones[i] = (short)0x3F80;  // bf16 1.0

  f32x16 acc0 = zero16(), acc1 = zero16(), accL = zero16();

  const int x7 = qv & 7;
  int off[4];
#pragma unroll
  for (int i = 0; i < 4; ++i) off[i] = ((2 * i + hi) ^ x7) << 3;

  const int srow = tid >> 3;
  const int sslot = tid & 7;
  const int sdst = srow * 64 + ((sslot ^ (srow & 7)) << 3);

  uint4 rk0, rk1, rv0, rv1;
#define LOADT2(rr)                                                                       \
  {                                                                                      \
    rk0 = *reinterpret_cast<const uint4*>(&kptr[((rr) * 128 + srow) * HDIM + sslot * 8]);     \
    rk1 = *reinterpret_cast<const uint4*>(&kptr[((rr) * 128 + 64 + srow) * HDIM + sslot * 8]);\
    rv0 = *reinterpret_cast<const uint4*>(&vptr[srow * SEQL + (rr) * 128 + sslot * 8]);       \
    rv1 = *reinterpret_cast<const uint4*>(&vptr[srow * SEQL + (rr) * 128 + 64 + sslot * 8]);  \
  }

  LOADT2(0);
  const int NR = SEQL / 128;  // 16 rounds, 2 KV-tiles each
  for (int r = 0; r < NR; ++r) {
    const int s = (r & 1) << 1;
    *reinterpret_cast<uint4*>(&Ks[s][sdst]) = rk0;
    *reinterpret_cast<uint4*>(&Ks[s + 1][sdst]) = rk1;
    *reinterpret_cast<uint4*>(&Vs[s][sdst]) = rv0;
    *reinterpret_cast<uint4*>(&Vs[s + 1][sdst]) = rv1;
    __syncthreads();
    if (r + 1 < NR) LOADT2(r + 1);  // 8 loads in flight under a full round (T14)

#pragma unroll
    for (int half = 0; half < 2; ++half) {
      const int c = s + half;

      f32x16 p0 = zero16(), p1 = zero16();
      __builtin_amdgcn_s_setprio(1);
#pragma unroll
      for (int kc = 0; kc < 4; ++kc) {
        bf16x8 ka0 = *reinterpret_cast<const bf16x8*>(&Ks[c][qv * 64 + off[kc]]);
        bf16x8 ka1 = *reinterpret_cast<const bf16x8*>(&Ks[c][(32 + qv) * 64 + off[kc]]);
        p0 = __builtin_amdgcn_mfma_f32_32x32x16_bf16(ka0, qb[kc], p0, 0, 0, 0);
        p1 = __builtin_amdgcn_mfma_f32_32x32x16_bf16(ka1, qb[kc], p1, 0, 0, 0);
      }
      __builtin_amdgcn_s_setprio(0);

#pragma unroll
      for (int i = 0; i < 16; ++i) {
        p0[i] = exp2_fast(p0[i]);
        p1[i] = exp2_fast(p1[i]);
      }

      bf16x8 pa[4];
#pragma unroll
      for (int ks = 0; ks < 4; ++ks) {
        const int o = 8 * (ks & 1);
        uint32_t X1, X2, Y1, Y2;
        if (ks < 2) {
          X1 = pkbf(p0[o + 0], p0[o + 1]); X2 = pkbf(p0[o + 2], p0[o + 3]);
          Y1 = pkbf(p0[o + 4], p0[o + 5]); Y2 = pkbf(p0[o + 6], p0[o + 7]);
        } else {
          X1 = pkbf(p1[o + 0], p1[o + 1]); X2 = pkbf(p1[o + 2], p1[o + 3]);
          Y1 = pkbf(p1[o + 4], p1[o + 5]); Y2 = pkbf(p1[o + 6], p1[o + 7]);
        }
        asm("v_permlane32_swap_b32 %0, %1" : "+v"(X1), "+v"(Y1));
        asm("v_permlane32_swap_b32 %0, %1" : "+v"(X2), "+v"(Y2));
        union { uint32_t u[4]; bf16x8 v; } uu;
        uu.u[0] = X1; uu.u[1] = X2; uu.u[2] = Y1; uu.u[3] = Y2;
        pa[ks] = uu.v;
      }

      __builtin_amdgcn_s_setprio(1);
#pragma unroll
      for (int ks = 0; ks < 4; ++ks) {
        bf16x8 vb0 = *reinterpret_cast<const bf16x8*>(&Vs[c][qv * 64 + off[ks]]);
        bf16x8 vb1 = *reinterpret_cast<const bf16x8*>(&Vs[c][(32 + qv) * 64 + off[ks]]);
        acc0 = __builtin_amdgcn_mfma_f32_32x32x16_bf16(pa[ks], vb0, acc0, 0, 0, 0);
        acc1 = __builtin_amdgcn_mfma_f32_32x32x16_bf16(pa[ks], vb1, acc1, 0, 0, 0);
        accL = __builtin_amdgcn_mfma_f32_32x32x16_bf16(pa[ks], ones, accL, 0, 0, 0);
      }
      __builtin_amdgcn_s_setprio(0);
    }
  }
#undef LOADT2

#pragma unroll
  for (int rg = 0; rg < 16; ++rg) {
    const int crow = (rg & 3) + 8 * (rg >> 2) + 4 * hi;
    const float invl = 1.f / accL[rg];
    const int qg = qg0 + crow;
    const size_t base = ((size_t)(b * SEQL + qg) * NHEAD + h) * HDIM + qv;
    attn_out[base] = f2bf(acc0[rg] * invl);
    attn_out[base + 32] = f2bf(acc1[rg] * invl);
  }
}

extern "C" void kernel_launch(void* const* d_in, const int* in_sizes, int n_in,
                              void* d_out, int out_size, void* d_ws, size_t ws_size,
                              hipStream_t stream) {
  const float* x  = (const float*)d_in[0];
  const float* Wq = (const float*)d_in[1];
  const float* bq = (const float*)d_in[2];
  const float* Wk = (const float*)d_in[3];
  const float* bk = (const float*)d_in[4];
  const float* Wv = (const float*)d_in[5];
  const float* bv = (const float*)d_in[6];
  const float* Wo = (const float*)d_in[7];
  const float* bo = (const float*)d_in[8];

  char* ws = (char*)d_ws;
  unsigned short* wqT = (unsigned short*)(ws);            // [3072][1024] contiguous q,k,v
  unsigned short* wkT = wqT + 1024 * 1024;
  unsigned short* wvT = wkT + 1024 * 1024;
  unsigned short* woT = wvT + 1024 * 1024;
  unsigned short* xb   = (unsigned short*)(ws + (size_t)(8 << 20));
  unsigned short* attn = xb;  // reuse: x_bf16 dead after QKV projection
  unsigned short* qw   = (unsigned short*)(ws + (size_t)(24 << 20));
  unsigned short* kw   = (unsigned short*)(ws + (size_t)(40 << 20));
  unsigned short* vtw  = (unsigned short*)(ws + (size_t)(56 << 20));

  transpose_convert4<<<dim3(16, 16, 4), 256, 0, stream>>>(Wq, Wk, Wv, Wo, wqT, wkT, wvT, woT);
  convert_x<<<MTOT * DM / 4 / 256, 256, 0, stream>>>(x, xb);

  gemm_qkv<<<dim3(24, 64), 256, 0, stream>>>(xb, wqT, bq, bk, bv, qw, kw, vtw);

  attn_kernel<<<512, 512, 0, stream>>>(qw, kw, vtw, attn);

  gemm_out<<<512, 256, 0, stream>>>(attn, woT, bo, (float*)d_out);
}

// Round 15
// 190.158 us; speedup vs baseline: 1.7771x; 1.0064x over previous
//
#include <hip/hip_runtime.h>
#include <hip/hip_bf16.h>
#include <stdint.h>

#define DM 1024
#define SEQL 2048
#define NBATCH 4
#define NHEAD 16
#define HDIM 64
#define MTOT (NBATCH * SEQL)  // 8192

using f32x4 = __attribute__((ext_vector_type(4))) float;
using f32x16 = __attribute__((ext_vector_type(16))) float;
using bf16x8 = __attribute__((ext_vector_type(8))) short;

static __device__ __forceinline__ unsigned short f2bf(float f) {
  union { float f; uint32_t u; } v; v.f = f;
  uint32_t u = v.u;
  return (unsigned short)((u + 0x7FFFu + ((u >> 16) & 1u)) >> 16);
}

static __device__ __forceinline__ float exp2_fast(float x) {
#if __has_builtin(__builtin_amdgcn_exp2f)
  return __builtin_amdgcn_exp2f(x);
#else
  float r;
  asm("v_exp_f32 %0, %1" : "=v"(r) : "v"(x));
  return r;
#endif
}

static __device__ __forceinline__ uint32_t pkbf(float lo, float hi) {
  float2 f; f.x = lo; f.y = hi;
  __hip_bfloat162 h = __float22bfloat162_rn(f);
  union { __hip_bfloat162 h; uint32_t u; } cv; cv.h = h;
  return cv.u;
}

static __device__ __forceinline__ f32x16 zero16() {
  f32x16 z;
#pragma unroll
  for (int i = 0; i < 16; ++i) z[i] = 0.f;
  return z;
}

static __device__ __forceinline__ void gload16(const void* g, void* l) {
  __builtin_amdgcn_global_load_lds(
      (const __attribute__((address_space(1))) unsigned int*)g,
      (__attribute__((address_space(3))) unsigned int*)l,
      16, 0, 0);
}

// ---------------- 4x weight transpose + f32->bf16 convert ----------------
__global__ __launch_bounds__(256) void transpose_convert4(
    const float* __restrict__ W0, const float* __restrict__ W1,
    const float* __restrict__ W2, const float* __restrict__ W3,
    unsigned short* __restrict__ T0, unsigned short* __restrict__ T1,
    unsigned short* __restrict__ T2, unsigned short* __restrict__ T3) {
  __shared__ float tile[64][65];
  const int z = blockIdx.z;
  const float* W = z == 0 ? W0 : z == 1 ? W1 : z == 2 ? W2 : W3;
  unsigned short* WT = z == 0 ? T0 : z == 1 ? T1 : z == 2 ? T2 : T3;
  const int bx = blockIdx.x;
  const int by = blockIdx.y;
  const int t = threadIdx.x;
  const int r = t >> 4;
  const int c4 = (t & 15) * 4;
#pragma unroll
  for (int i = 0; i < 4; ++i) {
    const float4 v = *reinterpret_cast<const float4*>(
        &W[(size_t)(by * 64 + r + i * 16) * DM + bx * 64 + c4]);
    tile[r + i * 16][c4 + 0] = v.x;
    tile[r + i * 16][c4 + 1] = v.y;
    tile[r + i * 16][c4 + 2] = v.z;
    tile[r + i * 16][c4 + 3] = v.w;
  }
  __syncthreads();
#pragma unroll
  for (int i = 0; i < 4; ++i) {
    const int rr = r + i * 16;
    uint32_t lo = (uint32_t)f2bf(tile[c4 + 0][rr]) | ((uint32_t)f2bf(tile[c4 + 1][rr]) << 16);
    uint32_t hi = (uint32_t)f2bf(tile[c4 + 2][rr]) | ((uint32_t)f2bf(tile[c4 + 3][rr]) << 16);
    uint2 o; o.x = lo; o.y = hi;
    *reinterpret_cast<uint2*>(&WT[(size_t)(bx * 64 + rr) * DM + by * 64 + c4]) = o;
  }
}

// ---------------- x f32 -> bf16 ----------------
__global__ __launch_bounds__(256) void convert_x(
    const float* __restrict__ x, unsigned short* __restrict__ xb) {
  const int i = blockIdx.x * 256 + threadIdx.x;
  const float4 v = reinterpret_cast<const float4*>(x)[i];
  uint2 o;
  o.x = (uint32_t)f2bf(v.x) | ((uint32_t)f2bf(v.y) << 16);
  o.y = (uint32_t)f2bf(v.z) | ((uint32_t)f2bf(v.w) << 16);
  reinterpret_cast<uint2*>(xb)[i] = o;
}

// 0.125 (1/sqrt(64)) * log2(e): scores come out in base-2 logits
#define QSCALE 0.1803368801111204f

// ---------------- fused QKV projection GEMM (R13, unchanged) --------------
__global__ __launch_bounds__(256) void gemm_qkv(
    const unsigned short* __restrict__ A, const unsigned short* __restrict__ BT,
    const float* __restrict__ bq, const float* __restrict__ bk, const float* __restrict__ bv,
    unsigned short* __restrict__ qo, unsigned short* __restrict__ ko,
    unsigned short* __restrict__ vo) {
  __shared__ unsigned short As[128][64];
  __shared__ unsigned short Bs[128][64];
  const int tid = threadIdx.x;
  const int w = tid >> 6;
  const int lane = tid & 63;
  const int wm = w >> 1, wn = w & 1;
  const int m0 = blockIdx.y * 128;
  const int n0 = blockIdx.x * 128;
  const int mode = n0 >> 10;
  const int lrow = lane & 15;
  const int lhi = lane >> 4;
  const int sRow = lane >> 3;
  const int sColSwz = ((lane & 7) ^ ((lane >> 3) & 7)) * 8;  // src pre-swizzle
  const int x7 = lrow & 7;

  unsigned short* dstA = (mode == 2) ? &Bs[0][0] : &As[0][0];
  unsigned short* dstB = (mode == 2) ? &As[0][0] : &Bs[0][0];

  f32x4 acc[4][4];
#pragma unroll
  for (int m = 0; m < 4; ++m)
#pragma unroll
    for (int n = 0; n < 4; ++n) acc[m][n] = (f32x4){0.f, 0.f, 0.f, 0.f};

  for (int k0 = 0; k0 < DM; k0 += 64) {
#pragma unroll
    for (int i = 0; i < 4; ++i) {
      const int rb = i * 32 + w * 8;
      gload16(&A[(size_t)(m0 + rb + sRow) * DM + k0 + sColSwz], dstA + rb * 64);
    }
#pragma unroll
    for (int i = 0; i < 4; ++i) {
      const int rb = i * 32 + w * 8;
      gload16(&BT[(size_t)(n0 + rb + sRow) * DM + k0 + sColSwz], dstB + rb * 64);
    }
    __syncthreads();
#pragma unroll
    for (int ks = 0; ks < 2; ++ks) {
      const int slot = ((ks * 4 + lhi) ^ x7) << 3;
      bf16x8 af[4], bfr[4];
#pragma unroll
      for (int m = 0; m < 4; ++m)
        af[m] = *reinterpret_cast<const bf16x8*>(&As[wm * 64 + m * 16 + lrow][slot]);
#pragma unroll
      for (int n = 0; n < 4; ++n)
        bfr[n] = *reinterpret_cast<const bf16x8*>(&Bs[wn * 64 + n * 16 + lrow][slot]);
#pragma unroll
      for (int m = 0; m < 4; ++m)
#pragma unroll
        for (int n = 0; n < 4; ++n)
          acc[m][n] = __builtin_amdgcn_mfma_f32_16x16x32_bf16(af[m], bfr[n], acc[m][n], 0, 0, 0);
    }
    __syncthreads();
  }

  if (mode < 2) {
    const bool isK = (mode == 1);
    unsigned short* dst = isK ? ko : qo;
    const float* bp = isK ? bk : bq;
    const float sc = isK ? 1.f : QSCALE;
#pragma unroll
    for (int n = 0; n < 4; ++n) {
      const int col = (n0 & 1023) + wn * 64 + n * 16 + lrow;
      const float bb = bp[col];
      const int hh = col >> 6, dd = col & 63;
#pragma unroll
      for (int m = 0; m < 4; ++m) {
        const int rowb = m0 + wm * 64 + m * 16 + lhi * 4;
#pragma unroll
        for (int r = 0; r < 4; ++r) {
          const int mg = rowb + r;
          const int bidx = mg >> 11;
          const int nn = mg & 2047;
          dst[((size_t)(bidx * NHEAD + hh) * SEQL + nn) * HDIM + dd] =
              f2bf((acc[m][n][r] + bb) * sc);
        }
      }
    }
  } else {
    // transposed tile: acc rows = V channels, cols = sequence
#pragma unroll
    for (int m = 0; m < 4; ++m) {
#pragma unroll
      for (int r = 0; r < 4; ++r) {
        const int dv = (n0 - 2048) + wm * 64 + m * 16 + lhi * 4 + r;
        const float bb = bv[dv];
        const int hh = dv >> 6, dd = dv & 63;
#pragma unroll
        for (int n = 0; n < 4; ++n) {
          const int seq = m0 + wn * 64 + n * 16 + lrow;
          const int bidx = seq >> 11;
          const int nn = seq & 2047;
          vo[((size_t)(bidx * NHEAD + hh) * HDIM + dd) * SEQL + nn] =
              f2bf(acc[m][n][r] + bb);
        }
      }
    }
  }
}

// ---------------- out-projection GEMM (R13, unchanged) --------------------
__global__ __launch_bounds__(256) void gemm_out(
    const unsigned short* __restrict__ A, const unsigned short* __restrict__ BT,
    const float* __restrict__ bias, float* __restrict__ Cout) {
  __shared__ unsigned short As[128][64];
  __shared__ unsigned short Bs[128][64];
  const int tid = threadIdx.x;
  const int w = tid >> 6;
  const int lane = tid & 63;
  const int wm = w >> 1, wn = w & 1;
  const int m0 = (blockIdx.x >> 3) * 128;
  const int n0 = (blockIdx.x & 7) * 128;
  const int lrow = lane & 15;
  const int lhi = lane >> 4;
  const int sRow = lane >> 3;
  const int sColSwz = ((lane & 7) ^ ((lane >> 3) & 7)) * 8;
  const int x7 = lrow & 7;

  f32x4 acc[4][4];
#pragma unroll
  for (int m = 0; m < 4; ++m)
#pragma unroll
    for (int n = 0; n < 4; ++n) acc[m][n] = (f32x4){0.f, 0.f, 0.f, 0.f};

  for (int k0 = 0; k0 < DM; k0 += 64) {
#pragma unroll
    for (int i = 0; i < 4; ++i) {
      const int rb = i * 32 + w * 8;
      gload16(&A[(size_t)(m0 + rb + sRow) * DM + k0 + sColSwz], &As[rb][0]);
    }
#pragma unroll
    for (int i = 0; i < 4; ++i) {
      const int rb = i * 32 + w * 8;
      gload16(&BT[(size_t)(n0 + rb + sRow) * DM + k0 + sColSwz], &Bs[rb][0]);
    }
    __syncthreads();
#pragma unroll
    for (int ks = 0; ks < 2; ++ks) {
      const int slot = ((ks * 4 + lhi) ^ x7) << 3;
      bf16x8 af[4], bfr[4];
#pragma unroll
      for (int m = 0; m < 4; ++m)
        af[m] = *reinterpret_cast<const bf16x8*>(&As[wm * 64 + m * 16 + lrow][slot]);
#pragma unroll
      for (int n = 0; n < 4; ++n)
        bfr[n] = *reinterpret_cast<const bf16x8*>(&Bs[wn * 64 + n * 16 + lrow][slot]);
#pragma unroll
      for (int m = 0; m < 4; ++m)
#pragma unroll
        for (int n = 0; n < 4; ++n)
          acc[m][n] = __builtin_amdgcn_mfma_f32_16x16x32_bf16(af[m], bfr[n], acc[m][n], 0, 0, 0);
    }
    __syncthreads();
  }

#pragma unroll
  for (int n = 0; n < 4; ++n) {
    const int col = n0 + wn * 64 + n * 16 + lrow;
    const float bb = bias[col];
#pragma unroll
    for (int m = 0; m < 4; ++m) {
      const int rowb = m0 + wm * 64 + m * 16 + lhi * 4;
#pragma unroll
      for (int r = 0; r < 4; ++r) {
        Cout[(size_t)(rowb + r) * DM + col] = acc[m][n][r] + bb;
      }
    }
  }
}

// ---------------- flash attention: 8 warps x 32 q-rows, 2 KV-tiles/round ---
// Sync structure BYTE-IDENTICAL to R10/R13 (passed twice): 4-set LDS, one
// __syncthreads per 2-tile round. Only the LAYOUT changes (validated correct
// by R14's first-check): row stride 72 elem (144 B) + linear slots -> bank
// group = (row+slot) mod 8, 8 lanes per 4-bank group = zero conflicts.
__global__ __launch_bounds__(512) void attn_kernel(
    const unsigned short* __restrict__ q, const unsigned short* __restrict__ k,
    const unsigned short* __restrict__ vt, unsigned short* __restrict__ attn_out) {
  __shared__ unsigned short Ks[4][64 * 72];  // [set*2+half][kv][d], stride 72
  __shared__ unsigned short Vs[4][64 * 72];  // [set*2+half][d][kv], stride 72

  const int bid = blockIdx.x;
  const int l0 = (bid & 7) * 64 + (bid >> 3);
  const int bh = l0 >> 3;
  const int qt = l0 & 7;
  const int b = bh >> 4, h = bh & 15;

  const int tid = threadIdx.x;
  const int w = tid >> 6;
  const int lane = tid & 63;
  const int qv = lane & 31;
  const int hi = lane >> 5;
  const int qg0 = qt * 256 + w * 32;

  const unsigned short* qptr = q + (size_t)bh * SEQL * HDIM;
  const unsigned short* kptr = k + (size_t)bh * SEQL * HDIM;
  const unsigned short* vptr = vt + (size_t)bh * HDIM * SEQL;

  bf16x8 qb[4];
#pragma unroll
  for (int kc = 0; kc < 4; ++kc)
    qb[kc] = *reinterpret_cast<const bf16x8*>(&qptr[(qg0 + qv) * HDIM + kc * 16 + hi * 8]);

  bf16x8 ones;
#pragma unroll
  for (int i = 0; i < 8; ++i) ones[i] = (short)0x3F80;  // bf16 1.0

  f32x16 acc0 = zero16(), acc1 = zero16(), accL = zero16();

  // linear slot offsets (no swizzle needed at stride 72)
  int off[4];
#pragma unroll
  for (int i = 0; i < 4; ++i) off[i] = (2 * i + hi) * 8;

  const int srow = tid >> 3;
  const int sslot = tid & 7;
  const int sdst = srow * 72 + sslot * 8;

  uint4 rk0, rk1, rv0, rv1;
#define LOADT2(rr)                                                                       \
  {                                                                                      \
    rk0 = *reinterpret_cast<const uint4*>(&kptr[((rr) * 128 + srow) * HDIM + sslot * 8]);     \
    rk1 = *reinterpret_cast<const uint4*>(&kptr[((rr) * 128 + 64 + srow) * HDIM + sslot * 8]);\
    rv0 = *reinterpret_cast<const uint4*>(&vptr[srow * SEQL + (rr) * 128 + sslot * 8]);       \
    rv1 = *reinterpret_cast<const uint4*>(&vptr[srow * SEQL + (rr) * 128 + 64 + sslot * 8]);  \
  }

  LOADT2(0);
  const int NR = SEQL / 128;  // 16 rounds, 2 KV-tiles each
  for (int r = 0; r < NR; ++r) {
    const int s = (r & 1) << 1;
    *reinterpret_cast<uint4*>(&Ks[s][sdst]) = rk0;
    *reinterpret_cast<uint4*>(&Ks[s + 1][sdst]) = rk1;
    *reinterpret_cast<uint4*>(&Vs[s][sdst]) = rv0;
    *reinterpret_cast<uint4*>(&Vs[s + 1][sdst]) = rv1;
    __syncthreads();
    if (r + 1 < NR) LOADT2(r + 1);  // 8 loads in flight under a full round (T14)

#pragma unroll
    for (int half = 0; half < 2; ++half) {
      const int c = s + half;

      f32x16 p0 = zero16(), p1 = zero16();
      __builtin_amdgcn_s_setprio(1);
#pragma unroll
      for (int kc = 0; kc < 4; ++kc) {
        bf16x8 ka0 = *reinterpret_cast<const bf16x8*>(&Ks[c][qv * 72 + off[kc]]);
        bf16x8 ka1 = *reinterpret_cast<const bf16x8*>(&Ks[c][(32 + qv) * 72 + off[kc]]);
        p0 = __builtin_amdgcn_mfma_f32_32x32x16_bf16(ka0, qb[kc], p0, 0, 0, 0);
        p1 = __builtin_amdgcn_mfma_f32_32x32x16_bf16(ka1, qb[kc], p1, 0, 0, 0);
      }
      __builtin_amdgcn_s_setprio(0);

#pragma unroll
      for (int i = 0; i < 16; ++i) {
        p0[i] = exp2_fast(p0[i]);
        p1[i] = exp2_fast(p1[i]);
      }

      bf16x8 pa[4];
#pragma unroll
      for (int ks = 0; ks < 4; ++ks) {
        const int o = 8 * (ks & 1);
        uint32_t X1, X2, Y1, Y2;
        if (ks < 2) {
          X1 = pkbf(p0[o + 0], p0[o + 1]); X2 = pkbf(p0[o + 2], p0[o + 3]);
          Y1 = pkbf(p0[o + 4], p0[o + 5]); Y2 = pkbf(p0[o + 6], p0[o + 7]);
        } else {
          X1 = pkbf(p1[o + 0], p1[o + 1]); X2 = pkbf(p1[o + 2], p1[o + 3]);
          Y1 = pkbf(p1[o + 4], p1[o + 5]); Y2 = pkbf(p1[o + 6], p1[o + 7]);
        }
        asm("v_permlane32_swap_b32 %0, %1" : "+v"(X1), "+v"(Y1));
        asm("v_permlane32_swap_b32 %0, %1" : "+v"(X2), "+v"(Y2));
        union { uint32_t u[4]; bf16x8 v; } uu;
        uu.u[0] = X1; uu.u[1] = X2; uu.u[2] = Y1; uu.u[3] = Y2;
        pa[ks] = uu.v;
      }

      __builtin_amdgcn_s_setprio(1);
#pragma unroll
      for (int ks = 0; ks < 4; ++ks) {
        bf16x8 vb0 = *reinterpret_cast<const bf16x8*>(&Vs[c][qv * 72 + off[ks]]);
        bf16x8 vb1 = *reinterpret_cast<const bf16x8*>(&Vs[c][(32 + qv) * 72 + off[ks]]);
        acc0 = __builtin_amdgcn_mfma_f32_32x32x16_bf16(pa[ks], vb0, acc0, 0, 0, 0);
        acc1 = __builtin_amdgcn_mfma_f32_32x32x16_bf16(pa[ks], vb1, acc1, 0, 0, 0);
        accL = __builtin_amdgcn_mfma_f32_32x32x16_bf16(pa[ks], ones, accL, 0, 0, 0);
      }
      __builtin_amdgcn_s_setprio(0);
    }
  }
#undef LOADT2

#pragma unroll
  for (int rg = 0; rg < 16; ++rg) {
    const int crow = (rg & 3) + 8 * (rg >> 2) + 4 * hi;
    const float invl = 1.f / accL[rg];
    const int qg = qg0 + crow;
    const size_t base = ((size_t)(b * SEQL + qg) * NHEAD + h) * HDIM + qv;
    attn_out[base] = f2bf(acc0[rg] * invl);
    attn_out[base + 32] = f2bf(acc1[rg] * invl);
  }
}

extern "C" void kernel_launch(void* const* d_in, const int* in_sizes, int n_in,
                              void* d_out, int out_size, void* d_ws, size_t ws_size,
                              hipStream_t stream) {
  const float* x  = (const float*)d_in[0];
  const float* Wq = (const float*)d_in[1];
  const float* bq = (const float*)d_in[2];
  const float* Wk = (const float*)d_in[3];
  const float* bk = (const float*)d_in[4];
  const float* Wv = (const float*)d_in[5];
  const float* bv = (const float*)d_in[6];
  const float* Wo = (const float*)d_in[7];
  const float* bo = (const float*)d_in[8];

  char* ws = (char*)d_ws;
  unsigned short* wqT = (unsigned short*)(ws);            // [3072][1024] contiguous q,k,v
  unsigned short* wkT = wqT + 1024 * 1024;
  unsigned short* wvT = wkT + 1024 * 1024;
  unsigned short* woT = wvT + 1024 * 1024;
  unsigned short* xb   = (unsigned short*)(ws + (size_t)(8 << 20));
  unsigned short* attn = xb;  // reuse: x_bf16 dead after QKV projection
  unsigned short* qw   = (unsigned short*)(ws + (size_t)(24 << 20));
  unsigned short* kw   = (unsigned short*)(ws + (size_t)(40 << 20));
  unsigned short* vtw  = (unsigned short*)(ws + (size_t)(56 << 20));

  transpose_convert4<<<dim3(16, 16, 4), 256, 0, stream>>>(Wq, Wk, Wv, Wo, wqT, wkT, wvT, woT);
  convert_x<<<MTOT * DM / 4 / 256, 256, 0, stream>>>(x, xb);

  gemm_qkv<<<dim3(24, 64), 256, 0, stream>>>(xb, wqT, bq, bk, bv, qw, kw, vtw);

  attn_kernel<<<512, 512, 0, stream>>>(qw, kw, vtw, attn);

  gemm_out<<<512, 256, 0, stream>>>(attn, woT, bo, (float*)d_out);
}